// Round 9
// baseline (1207.771 us; speedup 1.0000x reference)
//
#include <hip/hip_runtime.h>
#include <math.h>

#define NGRAPH 1000
#define NBK_MAX 1568      // buckets of 128 nodes: ceil(200000/128)=1563
#define PART_BLOCKS 512

typedef unsigned short ushort_t;
typedef __attribute__((ext_vector_type(8))) short short8;   // 8 bf16 (4 VGPRs)
typedef __attribute__((ext_vector_type(4))) float floatx4;  // MFMA accumulator

static __device__ inline ushort_t f2bf(float f) {
  unsigned u = __float_as_uint(f);
  u = (u + 0x7fffu + ((u >> 16) & 1u)) >> 16;  // RNE
  return (ushort_t)u;
}

// ---------------- Bucketed, atomic-free CSR build ----------------
// ebuf entries packed 4B: (src << 7) | (dst & 127)  [src < 2^18, bucket-local dst 7b]

__global__ __launch_bounds__(256) void bucket_hist(const int* __restrict__ dst, int E, int chunk,
                                                   int* __restrict__ hist, int nbk) {
  __shared__ int lh[NBK_MAX];
  for (int i = threadIdx.x; i < nbk; i += 256) lh[i] = 0;
  __syncthreads();
  const int e0 = blockIdx.x * chunk;
  const int e1 = min(E, e0 + chunk);
  for (int e = e0 + threadIdx.x; e < e1; e += 256) atomicAdd(&lh[dst[e] >> 7], 1);
  __syncthreads();
  int* row = hist + (size_t)blockIdx.x * nbk;
  for (int i = threadIdx.x; i < nbk; i += 256) row[i] = lh[i];
}

__global__ __launch_bounds__(256) void colscan(int* __restrict__ hist, int nbk, int nblk,
                                               int* __restrict__ totals) {
  int b = blockIdx.x * 256 + threadIdx.x;
  if (b >= nbk) return;
  int run = 0;
  for (int k = 0; k < nblk; k++) {
    int t = hist[(size_t)k * nbk + b];
    hist[(size_t)k * nbk + b] = run;
    run += t;
  }
  totals[b] = run;
}

__global__ __launch_bounds__(1024) void scan_small(const int* __restrict__ in, int n,
                                                   int* __restrict__ out) {
  __shared__ int s[2048];
  const int t = threadIdx.x;
  s[t] = (t < n) ? in[t] : 0;
  s[t + 1024] = (t + 1024 < n) ? in[t + 1024] : 0;
  __syncthreads();
  for (int off = 1; off < 2048; off <<= 1) {
    int v0 = (t >= off) ? s[t - off] : 0;
    int v1 = ((t + 1024) >= off) ? s[t + 1024 - off] : 0;
    __syncthreads();
    s[t] += v0;
    s[t + 1024] += v1;
    __syncthreads();
  }
  if (t < n) out[t] = (t == 0) ? 0 : s[t - 1];
  const int u = t + 1024;
  if (u < n) out[u] = s[u - 1];
  if (t == 0) out[n] = s[n - 1];
}

__global__ __launch_bounds__(256) void partition_kernel(const int* __restrict__ src,
                                                        const int* __restrict__ dst, int E,
                                                        int chunk, const int* __restrict__ hist,
                                                        const int* __restrict__ boff,
                                                        unsigned* __restrict__ ebuf, int nbk) {
  __shared__ int lbase[NBK_MAX];
  __shared__ int lcur[NBK_MAX];
  const int* row = hist + (size_t)blockIdx.x * nbk;
  for (int i = threadIdx.x; i < nbk; i += 256) {
    lbase[i] = boff[i] + row[i];
    lcur[i] = 0;
  }
  __syncthreads();
  const int e0 = blockIdx.x * chunk;
  const int e1 = min(E, e0 + chunk);
  for (int e = e0 + threadIdx.x; e < e1; e += 256) {
    int d = dst[e];
    int b = d >> 7;
    int pos = lbase[b] + atomicAdd(&lcur[b], 1);
    ebuf[pos] = ((unsigned)src[e] << 7) | (unsigned)(d & 127);
  }
}

__global__ __launch_bounds__(256) void bucket_csr(const unsigned* __restrict__ ebuf,
                                                  const int* __restrict__ boff,
                                                  int* __restrict__ row_ptr, int* __restrict__ col,
                                                  int N, int E) {
  __shared__ int cnt[128], exc[128], cur[128];
  const int b = blockIdx.x;
  const int node0 = b << 7;
  const int nn = min(128, N - node0);
  const int es = boff[b], ee = boff[b + 1];
  const int t = threadIdx.x;
  if (t < 128) cnt[t] = 0;
  __syncthreads();
  for (int e = es + t; e < ee; e += 256) atomicAdd(&cnt[ebuf[e] & 127u], 1);
  __syncthreads();
  if (t < 128) exc[t] = cnt[t];
  __syncthreads();
  for (int off = 1; off < 128; off <<= 1) {
    int v = 0;
    if (t < 128 && t >= off) v = exc[t - off];
    __syncthreads();
    if (t < 128) exc[t] += v;
    __syncthreads();
  }
  if (t < 128) {
    int ex = (t == 0) ? 0 : exc[t - 1];
    cur[t] = ex;
    if (t < nn) row_ptr[node0 + t] = es + ex;
  }
  __syncthreads();
  for (int e = es + t; e < ee; e += 256) {
    unsigned u = ebuf[e];
    int li = (int)(u & 127u);
    int pos = es + atomicAdd(&cur[li], 1);
    col[pos] = (int)(u >> 7);
  }
  if (b == 0 && t == 0) row_ptr[N] = E;
}

// ---------------- MFMA linear: y_bf16 = bf16(BN-affine(x_fp32)) . W1_bf16 ----------------
// B-frags in registers, A built on the fly. A layout: A[m=lane&15][k=quad*8+j];
// D layout: D[row=quad*4+r][col=lane&15] (learn_hip m89/m118 verified).

template <int FIN, int FOUT, bool HAS_BN>
__global__ __launch_bounds__(256) void lin_mfma(const float* __restrict__ x,
                                                const float* __restrict__ W,
                                                const float* __restrict__ stats,
                                                const float* __restrict__ gamma,
                                                const float* __restrict__ beta, float invN,
                                                ushort_t* __restrict__ y, int n) {
  constexpr int KC = FIN / 32;   // k-chunks (FIN in {64,32})
  constexpr int FT = FOUT / 16;  // feature tiles
  __shared__ ushort_t Wbf[FIN * FOUT];
  __shared__ float scv[FIN], ofv[FIN];
  const int tid = threadIdx.x;
  for (int i = tid; i < FIN * FOUT; i += 256) Wbf[i] = f2bf(W[i]);
  for (int i = tid; i < FIN; i += 256) {
    if (HAS_BN) {
      float mu = stats[i] * invN;
      float var = stats[128 + i] * invN - mu * mu;
      float s = gamma[i] * rsqrtf(var + 1e-5f);
      scv[i] = s;
      ofv[i] = beta[i] - s * mu;
    } else {
      scv[i] = 1.f;
      ofv[i] = 0.f;
    }
  }
  __syncthreads();
  const int lane = tid & 63, wv = tid >> 6;
  const int colf = lane & 15, quad = lane >> 4, kbase = quad * 8;

  short8 Bf[FT][KC];
#pragma unroll
  for (int t = 0; t < FT; t++)
#pragma unroll
    for (int c = 0; c < KC; c++)
#pragma unroll
      for (int j = 0; j < 8; j++)
        Bf[t][c][j] = (short)Wbf[(c * 32 + kbase + j) * FOUT + t * 16 + colf];

  const floatx4 zero4 = {0.f, 0.f, 0.f, 0.f};
  const int ntiles = (n + 15) >> 4;
  for (int nt = blockIdx.x * 4 + wv; nt < ntiles; nt += gridDim.x * 4) {
    const int node0 = nt << 4;
    const int anode = node0 + colf;
    short8 Af[KC];
#pragma unroll
    for (int c = 0; c < KC; c++) {
      if (anode < n) {
        const int kk = c * 32 + kbase;
        const float* xp = x + (size_t)anode * FIN + kk;
        float4 xa = *(const float4*)xp;
        float4 xb = *(const float4*)(xp + 4);
        Af[c][0] = (short)f2bf(fmaf(xa.x, scv[kk + 0], ofv[kk + 0]));
        Af[c][1] = (short)f2bf(fmaf(xa.y, scv[kk + 1], ofv[kk + 1]));
        Af[c][2] = (short)f2bf(fmaf(xa.z, scv[kk + 2], ofv[kk + 2]));
        Af[c][3] = (short)f2bf(fmaf(xa.w, scv[kk + 3], ofv[kk + 3]));
        Af[c][4] = (short)f2bf(fmaf(xb.x, scv[kk + 4], ofv[kk + 4]));
        Af[c][5] = (short)f2bf(fmaf(xb.y, scv[kk + 5], ofv[kk + 5]));
        Af[c][6] = (short)f2bf(fmaf(xb.z, scv[kk + 6], ofv[kk + 6]));
        Af[c][7] = (short)f2bf(fmaf(xb.w, scv[kk + 7], ofv[kk + 7]));
      } else {
        Af[c] = short8{0, 0, 0, 0, 0, 0, 0, 0};
      }
    }
#pragma unroll
    for (int t = 0; t < FT; t++) {
      floatx4 acc = zero4;
#pragma unroll
      for (int c = 0; c < KC; c++)
        acc = __builtin_amdgcn_mfma_f32_16x16x32_bf16(Af[c], Bf[t][c], acc, 0, 0, 0);
#pragma unroll
      for (int r = 0; r < 4; r++) {
        const int row = node0 + quad * 4 + r;
        if (row < n) y[(size_t)row * FOUT + t * 16 + colf] = f2bf(acc[r]);
      }
    }
  }
}

// ---------------- MFMA second linear: h_fp32 = m_bf16 . W2_bf16 + b2 (+ BN stats) ----------

template <int F>
__global__ __launch_bounds__(256) void lin2s_mfma(const ushort_t* __restrict__ m,
                                                  const float* __restrict__ W,
                                                  const float* __restrict__ b,
                                                  float* __restrict__ h,
                                                  float* __restrict__ stats, int n) {
  constexpr int KC = (F + 31) / 32;  // 2,1,1
  constexpr int FT = F / 16;         // 4,2,1
  __shared__ ushort_t Wbf[F * F];
  __shared__ float bs[F], ls[F], lsq[F];
  const int tid = threadIdx.x;
  for (int i = tid; i < F * F; i += 256) Wbf[i] = f2bf(W[i]);
  if (tid < F) {
    bs[tid] = b[tid];
    ls[tid] = 0.f;
    lsq[tid] = 0.f;
  }
  __syncthreads();
  const int lane = tid & 63, wv = tid >> 6;
  const int colf = lane & 15, quad = lane >> 4, kbase = quad * 8;

  short8 Bf[FT][KC];
#pragma unroll
  for (int t = 0; t < FT; t++)
#pragma unroll
    for (int c = 0; c < KC; c++)
#pragma unroll
      for (int j = 0; j < 8; j++) {
        const int k = c * 32 + kbase + j;
        Bf[t][c][j] = (k < F) ? (short)Wbf[k * F + t * 16 + colf] : (short)0;
      }

  const floatx4 zero4 = {0.f, 0.f, 0.f, 0.f};
  float ssum[FT], ssq[FT];
#pragma unroll
  for (int t = 0; t < FT; t++) {
    ssum[t] = 0.f;
    ssq[t] = 0.f;
  }

  const int ntiles = (n + 15) >> 4;
  for (int nt = blockIdx.x * 4 + wv; nt < ntiles; nt += gridDim.x * 4) {
    const int node0 = nt << 4;
    const int anode = node0 + colf;
    short8 Af[KC];
#pragma unroll
    for (int c = 0; c < KC; c++) {
      const int kk = c * 32 + kbase;
      if (anode < n && kk < F)
        Af[c] = *(const short8*)(m + (size_t)anode * F + kk);
      else
        Af[c] = short8{0, 0, 0, 0, 0, 0, 0, 0};
    }
#pragma unroll
    for (int t = 0; t < FT; t++) {
      floatx4 acc = zero4;
#pragma unroll
      for (int c = 0; c < KC; c++)
        acc = __builtin_amdgcn_mfma_f32_16x16x32_bf16(Af[c], Bf[t][c], acc, 0, 0, 0);
      const float bv = bs[t * 16 + colf];
#pragma unroll
      for (int r = 0; r < 4; r++) {
        const int row = node0 + quad * 4 + r;
        if (row < n) {
          float o = acc[r] + bv;
          h[(size_t)row * F + t * 16 + colf] = o;
          ssum[t] += o;
          ssq[t] += o * o;
        }
      }
    }
  }
#pragma unroll
  for (int t = 0; t < FT; t++) {
    atomicAdd(&ls[t * 16 + colf], ssum[t]);
    atomicAdd(&lsq[t * 16 + colf], ssq[t]);
  }
  __syncthreads();
  if (tid < F) {
    atomicAdd(&stats[tid], ls[tid]);
    atomicAdd(&stats[128 + tid], lsq[tid]);
  }
}

// ---------------- Gather (bf16 rows, fp32 accum): m_bf16 = ReLU((1+eps)*y_i + sum y_j + b1) ----

template <int F>
__global__ __launch_bounds__(256) void aggrelu_b(const ushort_t* __restrict__ y,
                                                 const int* __restrict__ row_ptr,
                                                 const int* __restrict__ col,
                                                 const float* __restrict__ epsp,
                                                 const float* __restrict__ b1,
                                                 ushort_t* __restrict__ m, int n) {
  constexpr int LPN = F / 8;      // 16B bf16x8 per lane
  constexpr int NPB = 256 / LPN;  // 32 / 64 / 128 nodes per block
  const int tid = threadIdx.x;
  const int ln = tid / LPN;
  const int fl = tid % LPN;
  const float e1 = 1.0f + epsp[0];
  const float4 b1a = ((const float4*)b1)[fl * 2];
  const float4 b1b = ((const float4*)b1)[fl * 2 + 1];

  const int node = blockIdx.x * NPB + ln;
  if (node >= n) return;
  const uint4* yr = (const uint4*)y;
  const size_t rowi = (size_t)node * LPN + fl;
  const int rs = row_ptr[node], re = row_ptr[node + 1];

  float acc[8];
#pragma unroll
  for (int j = 0; j < 8; j++) acc[j] = 0.f;

  auto addv = [&](uint4 v) {
    acc[0] += __uint_as_float(v.x << 16);
    acc[1] += __uint_as_float(v.x & 0xffff0000u);
    acc[2] += __uint_as_float(v.y << 16);
    acc[3] += __uint_as_float(v.y & 0xffff0000u);
    acc[4] += __uint_as_float(v.z << 16);
    acc[5] += __uint_as_float(v.z & 0xffff0000u);
    acc[6] += __uint_as_float(v.w << 16);
    acc[7] += __uint_as_float(v.w & 0xffff0000u);
  };

  int e = rs;
  for (; e + 4 <= re; e += 4) {
    int c0 = col[e], c1 = col[e + 1], c2 = col[e + 2], c3 = col[e + 3];
    uint4 v0 = yr[(size_t)c0 * LPN + fl];
    uint4 v1 = yr[(size_t)c1 * LPN + fl];
    uint4 v2 = yr[(size_t)c2 * LPN + fl];
    uint4 v3 = yr[(size_t)c3 * LPN + fl];
    addv(v0);
    addv(v1);
    addv(v2);
    addv(v3);
  }
  for (; e < re; e++) addv(yr[(size_t)col[e] * LPN + fl]);

  uint4 sv = yr[rowi];
  float r0, r1, r2, r3, r4, r5, r6, r7;
  r0 = fmaxf(fmaf(e1, __uint_as_float(sv.x << 16), acc[0]) + b1a.x, 0.f);
  r1 = fmaxf(fmaf(e1, __uint_as_float(sv.x & 0xffff0000u), acc[1]) + b1a.y, 0.f);
  r2 = fmaxf(fmaf(e1, __uint_as_float(sv.y << 16), acc[2]) + b1a.z, 0.f);
  r3 = fmaxf(fmaf(e1, __uint_as_float(sv.y & 0xffff0000u), acc[3]) + b1a.w, 0.f);
  r4 = fmaxf(fmaf(e1, __uint_as_float(sv.z << 16), acc[4]) + b1b.x, 0.f);
  r5 = fmaxf(fmaf(e1, __uint_as_float(sv.z & 0xffff0000u), acc[5]) + b1b.y, 0.f);
  r6 = fmaxf(fmaf(e1, __uint_as_float(sv.w << 16), acc[6]) + b1b.z, 0.f);
  r7 = fmaxf(fmaf(e1, __uint_as_float(sv.w & 0xffff0000u), acc[7]) + b1b.w, 0.f);
  uint4 o;
  o.x = (unsigned)f2bf(r0) | ((unsigned)f2bf(r1) << 16);
  o.y = (unsigned)f2bf(r2) | ((unsigned)f2bf(r3) << 16);
  o.z = (unsigned)f2bf(r4) | ((unsigned)f2bf(r5) << 16);
  o.w = (unsigned)f2bf(r6) | ((unsigned)f2bf(r7) << 16);
  ((uint4*)m)[rowi] = o;
}

// ---------------- Graph segment starts (batch is sorted) ----------------

__global__ __launch_bounds__(256) void gstart_kernel(const int* __restrict__ batch, int n,
                                                     int* __restrict__ gstart, int ng) {
  int g = blockIdx.x * blockDim.x + threadIdx.x;
  if (g > ng) return;
  int lo = 0, hi = n;
  while (lo < hi) {
    int mid = (lo + hi) >> 1;
    if (batch[mid] < g) lo = mid + 1; else hi = mid;
  }
  gstart[g] = lo;
}

// ---------------- Fused readout: BN3-affine + mean + att-c + gated pool ----------------

__global__ __launch_bounds__(256) void readout_fused(
    const float* __restrict__ h3, const int* __restrict__ gstart,
    const float* __restrict__ stats, const float* __restrict__ gamma,
    const float* __restrict__ beta, float invN, const float* __restrict__ attW,
    const float* __restrict__ attb, float* __restrict__ hg, int ng) {
  __shared__ float sM[16], oM[16], red[16][17], meanM[16], cM[16];
  const int tid = threadIdx.x;
  const int g = blockIdx.x;
  const int f = tid & 15, slot = tid >> 4;
  if (tid < 16) {
    float mu = stats[tid] * invN;
    float var = stats[128 + tid] * invN - mu * mu;
    float s = gamma[tid] * rsqrtf(var + 1e-5f);
    sM[tid] = s;
    oM[tid] = beta[tid] - s * mu;
  }
  __syncthreads();
  const int s0 = gstart[g], e0 = gstart[g + 1];
  const float sf = sM[f], of = oM[f];

  float acc = 0.f;
  for (int node = s0 + slot; node < e0; node += 16)
    acc += fmaf(h3[(size_t)node * 16 + f], sf, of);
  red[slot][f] = acc;
  __syncthreads();
  if (tid < 16) {
    float t = 0.f;
    for (int s = 0; s < 16; s++) t += red[s][tid];
    meanM[tid] = t / fmaxf((float)(e0 - s0), 1.f);
  }
  __syncthreads();
  if (tid < 16) {
    float a = attb[tid];
    for (int k = 0; k < 16; k++) a += meanM[k] * attW[k * 16 + tid];
    cM[tid] = 1.f / (1.f + expf(-a));
  }
  __syncthreads();
  const float cf = cM[f];
  float acc2 = 0.f;
  for (int node = s0 + slot; node < e0; node += 16) {
    float xv = fmaf(h3[(size_t)node * 16 + f], sf, of);
    float p = xv * cf;
    for (int m = 8; m >= 1; m >>= 1) p += __shfl_xor(p, m, 16);
    acc2 += xv / (1.f + expf(-p));
  }
  red[slot][f] = acc2;
  __syncthreads();
  if (tid < 16) {
    float t = 0.f;
    for (int s = 0; s < 16; s++) t += red[s][tid];
    hg[g * 16 + tid] = t;
  }
}

// ---------------- EFN + final: 16 lanes per graph, weights + vectors in LDS ----------------

__global__ __launch_bounds__(256) void final3_kernel(
    const float* __restrict__ hgA, const float* __restrict__ hgB, const float* __restrict__ aW1,
    const float* __restrict__ ab1, const float* __restrict__ aW2, const float* __restrict__ ab2,
    const float* __restrict__ mW, const float* __restrict__ mb, const float* __restrict__ fcW1,
    const float* __restrict__ fcb1, const float* __restrict__ fcW2,
    const float* __restrict__ fcb2, float* __restrict__ out, int ng) {
  __shared__ float aW1s[256], aW2s[256], mWs[512], fcW1s[128];
  __shared__ float ab1s[8], ab2s[32], mbs[16], fcb1s[8], fcW2s[8];
  __shared__ float fcb2s;
  __shared__ float hb[16][33], m8b[16][9], encb[16][33], abb[16][17], tb[16][9];
  const int tid = threadIdx.x;
  aW1s[tid] = aW1[tid];
  aW2s[tid] = aW2[tid];
  mWs[tid] = mW[tid];
  mWs[256 + tid] = mW[256 + tid];
  if (tid < 128) fcW1s[tid] = fcW1[tid];
  if (tid < 8) {
    ab1s[tid] = ab1[tid];
    fcb1s[tid] = fcb1[tid];
    fcW2s[tid] = fcW2[tid];
  }
  if (tid < 32) ab2s[tid] = ab2[tid];
  if (tid < 16) mbs[tid] = mb[tid];
  if (tid == 0) fcb2s = fcb2[0];
  __syncthreads();

  const int g = tid >> 4;
  const int l = tid & 15;
  const int gg = blockIdx.x * 16 + g;
  const bool valid = gg < ng;
  const float hiv = valid ? hgA[gg * 16 + l] : 0.f;
  const float hjv = valid ? hgB[gg * 16 + l] : 0.f;
  float res[3];

#pragma unroll
  for (int p = 0; p < 3; p++) {
    float ha = (p == 2) ? hjv : hiv;
    float h2 = (p == 1) ? hiv : hjv;
    hb[g][l] = ha;
    hb[g][16 + l] = h2;
    __syncthreads();
    if (l < 8) {
      float t = ab1s[l];
#pragma unroll
      for (int k = 0; k < 32; k++) t += hb[g][k] * aW1s[k * 8 + l];
      m8b[g][l] = fmaxf(t, 0.f);
    }
    __syncthreads();
    float e0 = ab2s[l], e1 = ab2s[16 + l];
#pragma unroll
    for (int k = 0; k < 8; k++) {
      float mv = m8b[g][k];
      e0 += mv * aW2s[k * 32 + l];
      e1 += mv * aW2s[k * 32 + 16 + l];
    }
    float a0 = tanhf(e0), a1 = tanhf(e1);
    encb[g][l] = fmaf(a0, ha, ha);
    encb[g][16 + l] = fmaf(a1, h2, h2);
    __syncthreads();
    float o = mbs[l];
#pragma unroll
    for (int k = 0; k < 32; k++) o += encb[g][k] * mWs[k * 16 + l];
    res[p] = fmaxf(o, 0.f);
    __syncthreads();
  }

  if (valid) {
    out[ng + gg * 16 + l] = res[0] - res[2];            // h_Ab = AB - BB
    out[ng + ng * 16 + gg * 16 + l] = res[0] - res[1];  // h_aB = AB - AA
  }
  abb[g][l] = res[0];
  __syncthreads();
  if (l < 8) {
    float t = fcb1s[l];
#pragma unroll
    for (int k = 0; k < 16; k++) t += abb[g][k] * fcW1s[k * 8 + l];
    tb[g][l] = fmaxf(t, 0.f);
  }
  __syncthreads();
  if (l == 0 && valid) {
    float sc = fcb2s;
#pragma unroll
    for (int o = 0; o < 8; o++) sc += tb[g][o] * fcW2s[o];
    out[gg] = sc;
  }
}

// ---------------- Launch ----------------

extern "C" void kernel_launch(void* const* d_in, const int* in_sizes, int n_in, void* d_out,
                              int out_size, void* d_ws, size_t ws_size, hipStream_t stream) {
  (void)n_in;
  (void)out_size;
  (void)ws_size;
  const int N = in_sizes[0] / 64;
  const int E = in_sizes[2] / 2;
  const int NG = NGRAPH;
  const int NBK = (N + 127) >> 7;
  const int CHUNK = (E + PART_BLOCKS - 1) / PART_BLOCKS;

  char* w = (char*)d_ws;
  auto alloc = [&](size_t bytes) -> void* {
    void* p = (void*)w;
    w += (bytes + 255) & ~(size_t)255;
    return p;
  };
  int* row_ptr = (int*)alloc((size_t)(N + 1) * 4);
  int* col = (int*)alloc((size_t)E * 4);
  int* hist = (int*)alloc((size_t)PART_BLOCKS * NBK * 4);
  int* totals = (int*)alloc((size_t)NBK * 4);
  int* boff = (int*)alloc((size_t)(NBK + 1) * 4);
  float* bufA = (float*)alloc((size_t)N * 64 * 4);
  float* bufB = (float*)alloc((size_t)N * 64 * 4);
  float* stats = (float*)alloc(3 * 256 * 4);
  int* gstart = (int*)alloc((size_t)(NG + 1) * 4);
  float* hgA = (float*)alloc((size_t)NG * 16 * 4);
  float* hgB = (float*)alloc((size_t)NG * 16 * 4);

  // Aliases (disjoint live ranges), m buffers bf16:
  unsigned* ebuf = (unsigned*)bufA;                    // CSR staging 12.8 MB; dead before L1
  ushort_t* y1 = (ushort_t*)bufB;                      // bf16 N*64 = 25.6 MB
  ushort_t* m1 = (ushort_t*)bufA;                      // bf16 N*64 (over dead ebuf)
  float* h1 = bufB;                                    // fp32 N*64 (y1 dead)
  ushort_t* y2 = (ushort_t*)bufA;                      // bf16 N*32 = 12.8 MB (m1 dead)
  ushort_t* m2 = (ushort_t*)(bufA + (size_t)N * 16);   // bf16 N*32 @ +12.8 MB
  float* h2 = bufB;                                    // fp32 N*32 (h1 dead)
  ushort_t* y3 = (ushort_t*)bufA;                      // bf16 N*16 = 6.4 MB
  ushort_t* m3 = (ushort_t*)(bufA + (size_t)N * 8);    // bf16 N*16 @ +6.4 MB
  float* h3 = bufB;                                    // fp32 N*16 (h2 dead)

  const float* attW = (const float*)d_in[27];
  const float* attb = (const float*)d_in[28];
  const float invN = 1.0f / (float)N;

  for (int s = 0; s < 2; s++) {
    const float* x0 = (const float*)d_in[s];
    const int* esrc = (const int*)d_in[2 + s];
    const int* edst = esrc + E;
    const int* batch = (const int*)d_in[4 + s];
    float* hg = s ? hgB : hgA;

    // ---- bucketed CSR build (no global atomics) ----
    bucket_hist<<<PART_BLOCKS, 256, 0, stream>>>(edst, E, CHUNK, hist, NBK);
    colscan<<<(NBK + 255) / 256, 256, 0, stream>>>(hist, NBK, PART_BLOCKS, totals);
    scan_small<<<1, 1024, 0, stream>>>(totals, NBK, boff);
    partition_kernel<<<PART_BLOCKS, 256, 0, stream>>>(esrc, edst, E, CHUNK, hist, boff, ebuf,
                                                      NBK);
    bucket_csr<<<NBK, 256, 0, stream>>>(ebuf, boff, row_ptr, col, N, E);

    hipMemsetAsync(stats, 0, 3 * 256 * 4, stream);

    // ---- layer 1 ----
    lin_mfma<64, 64, false><<<512, 256, 0, stream>>>(
        x0, (const float*)d_in[7], nullptr, nullptr, nullptr, invN, y1, N);
    aggrelu_b<64><<<(N + 31) / 32, 256, 0, stream>>>(
        y1, row_ptr, col, (const float*)d_in[6], (const float*)d_in[8], m1, N);
    lin2s_mfma<64><<<512, 256, 0, stream>>>(m1, (const float*)d_in[9], (const float*)d_in[10],
                                            h1, stats, N);

    // ---- layer 2 ----
    lin_mfma<64, 32, true><<<512, 256, 0, stream>>>(
        h1, (const float*)d_in[14], stats, (const float*)d_in[11], (const float*)d_in[12], invN,
        y2, N);
    aggrelu_b<32><<<(N + 63) / 64, 256, 0, stream>>>(
        y2, row_ptr, col, (const float*)d_in[13], (const float*)d_in[15], m2, N);
    lin2s_mfma<32><<<512, 256, 0, stream>>>(m2, (const float*)d_in[16], (const float*)d_in[17],
                                            h2, stats + 256, N);

    // ---- layer 3 ----
    lin_mfma<32, 16, true><<<512, 256, 0, stream>>>(
        h2, (const float*)d_in[21], stats + 256, (const float*)d_in[18], (const float*)d_in[19],
        invN, y3, N);
    aggrelu_b<16><<<(N + 127) / 128, 256, 0, stream>>>(
        y3, row_ptr, col, (const float*)d_in[20], (const float*)d_in[22], m3, N);
    lin2s_mfma<16><<<512, 256, 0, stream>>>(m3, (const float*)d_in[23], (const float*)d_in[24],
                                            h3, stats + 512, N);

    // ---- fused readout (BN3 folded; batch sorted -> segment-parallel, no atomics) ----
    gstart_kernel<<<(NG + 256) / 256, 256, 0, stream>>>(batch, N, gstart, NG);
    readout_fused<<<NG, 256, 0, stream>>>(h3, gstart, stats + 512, (const float*)d_in[25],
                                          (const float*)d_in[26], invN, attW, attb, hg, NG);
  }

  final3_kernel<<<(NG + 15) / 16, 256, 0, stream>>>(
      hgA, hgB, (const float*)d_in[29], (const float*)d_in[30], (const float*)d_in[31],
      (const float*)d_in[32], (const float*)d_in[33], (const float*)d_in[34],
      (const float*)d_in[35], (const float*)d_in[36], (const float*)d_in[37],
      (const float*)d_in[38], (float*)d_out, NG);
}